// Round 3
// baseline (5111.459 us; speedup 1.0000x reference)
//
#include <hip/hip_runtime.h>
#include <math.h>

#define EMB 768
#define NH 12
#define HD 64
#define NL 12
#define NV 50257
#define MAXS 1024
#define S_PAST 1023
#define E3 2304
#define E4 3072

#define NCOMP 384
#define NCOPY 128
#define NBLK (NCOMP + NCOPY)

// ws float offsets
#define WS_SYNC 0            // 128 u32 barrier counters (memset to 0 each call)
#define WS_H    128
#define WS_QKV  (WS_H + EMB)
#define WS_FC   (WS_QKV + E3)
#define WS_PART (WS_FC + E4)     // 192 entries * 68 floats = 13056

typedef unsigned int uint32;

__device__ __forceinline__ uint32 aload(uint32* p) {
  return __hip_atomic_load(p, __ATOMIC_RELAXED, __HIP_MEMORY_SCOPE_AGENT);
}

// grid barrier over the NCOMP compute blocks; one fresh counter per stage
__device__ __forceinline__ void gbar(uint32* cnt, int stage) {
  __threadfence();
  __syncthreads();
  if (threadIdx.x == 0) {
    uint32* c = cnt + stage;
    atomicAdd(c, 1u);
    while (aload(c) < (uint32)NCOMP) __builtin_amdgcn_s_sleep(1);
  }
  __syncthreads();
  __threadfence();
}

__device__ __forceinline__ void blockReduce2(float& a, float& b, volatile float* ra, volatile float* rb) {
  int lane = threadIdx.x & 63, wid = threadIdx.x >> 6;
#pragma unroll
  for (int o = 32; o > 0; o >>= 1) { a += __shfl_down(a, o); b += __shfl_down(b, o); }
  if (lane == 0) { ra[wid] = a; rb[wid] = b; }
  __syncthreads();
  if (threadIdx.x == 0) {
    ra[0] = ra[0] + ra[1] + ra[2] + ra[3];
    rb[0] = rb[0] + rb[1] + rb[2] + rb[3];
  }
  __syncthreads();
  a = ra[0]; b = rb[0];
}

__device__ __forceinline__ void ln_stats(const float* __restrict__ h, volatile float* ra,
                                         volatile float* rb, float& mean, float& rstd) {
  float s1 = 0.f, s2 = 0.f;
  int tid = threadIdx.x;
#pragma unroll
  for (int e = tid; e < EMB; e += 256) { float v = h[e]; s1 += v; s2 += v * v; }
  blockReduce2(s1, s2, ra, rb);
  mean = s1 * (1.f / EMB);
  float var = s2 * (1.f / EMB) - mean * mean;
  rstd = rsqrtf(var + 1e-5f);
}

// tile GEMV: nrows (16 or 24) rows of W (row-major, n4 float4 per row) x 256 output cols
// xs[nrows] input; out pre-offset to col block; bias (nullable) pre-offset to col block
__device__ __forceinline__ void gemv_rows(int nrows, const float* xs, const float4* W4, int n4,
                                          float* out, float4* red4, const float* bias) {
  int tid = threadIdx.x, lane = tid & 63, wid = tid >> 6;
  int per = nrows >> 2;
  float4 acc = {0.f, 0.f, 0.f, 0.f};
  const float4* p = W4 + (size_t)(wid * per) * n4 + lane;
#pragma unroll
  for (int i = 0; i < 6; i++) {
    if (i < per) {
      float x = xs[wid * per + i];
      float4 w = p[(size_t)i * n4];
      acc.x += x * w.x; acc.y += x * w.y; acc.z += x * w.z; acc.w += x * w.w;
    }
  }
  red4[wid * 64 + lane] = acc;
  __syncthreads();
  if (wid == 0) {
    float4 a0 = red4[lane], a1 = red4[64 + lane], a2 = red4[128 + lane], a3 = red4[192 + lane];
    float rx = a0.x + a1.x + a2.x + a3.x;
    float ry = a0.y + a1.y + a2.y + a3.y;
    float rz = a0.z + a1.z + a2.z + a3.z;
    float rw = a0.w + a1.w + a2.w + a3.w;
    if (bias) { rx += bias[lane * 4]; ry += bias[lane * 4 + 1]; rz += bias[lane * 4 + 2]; rw += bias[lane * 4 + 3]; }
    float* op = out + (size_t)lane * 4;
    atomicAdd(op + 0, rx); atomicAdd(op + 1, ry);
    atomicAdd(op + 2, rz); atomicAdd(op + 3, rw);
  }
  __syncthreads();
}

// ---- stages (each compute block: uniform trip counts; gbar called outside) ----

__device__ void stage_embed(int bi, const int* ids, const float* wte, const float* wpe,
                            const float* attn_b, float* h, float* qkv) {
  int tid = threadIdx.x;
  for (int t = bi; t < 10; t += NCOMP) {
    if (t == 0) {
      int id = ids[0];
      for (int e = tid; e < EMB; e += 256)
        h[e] = wte[(size_t)id * EMB + e] + wpe[(size_t)S_PAST * EMB + e];
    } else {
      int k = t - 1;
      qkv[k * 256 + tid] = attn_b[k * 256 + tid];
    }
  }
}

__device__ void stage_ln_gemv(int bi, const float* h, const float* g, const float* b,
                              const float* W, float* out, int N, int l, int njt, float* sm) {
  float4* red4 = (float4*)sm;
  float* xs = sm + 1024;
  volatile float* ra = sm + 1088; volatile float* rb = sm + 1092;
  int NT = njt * 32;
  int n4 = N >> 2;
  int tid = threadIdx.x;
  for (int t = bi; t < NT; t += NCOMP) {
    int jt = t % njt, et = t / njt;
    int r0 = et * 24, c0 = jt * 256;
    float mean, rstd;
    ln_stats(h, ra, rb, mean, rstd);
    if (tid < 24) {
      int e = r0 + tid;
      xs[tid] = (h[e] - mean) * rstd * g[l * EMB + e] + b[l * EMB + e];
    }
    __syncthreads();
    const float4* W4 = (const float4*)(W + (size_t)l * EMB * N) + (size_t)r0 * n4 + (c0 >> 2);
    gemv_rows(24, xs, W4, n4, out + c0, red4, nullptr);
  }
}

__device__ void stage_attn(int bi, const float* qkv, const float* pk, const float* pv,
                           const float* mask, const float* fc_b,
                           float* opk, float* opv, float* part, float* wfc, int l, float* sm) {
  const int NT = 204;
  int tid = threadIdx.x;
  for (int t = bi; t < NT; t += NCOMP) {
    if (t < 192) {
      int h = t >> 4, c = t & 15;
      float* qs = sm;                       // 64
      float* sc = sm + 64;                  // 64
      float4* redo = (float4*)(sm + 128);   // 64 float4
      int sub = tid & 15, grp = tid >> 4;
      int lane = tid & 63, wid = tid >> 6;
      if (tid < 64) qs[tid] = qkv[h * 64 + tid];
      __syncthreads();
      size_t base = ((size_t)(l * NH + h) * MAXS) * HD;
      const float4* K4 = (const float4*)(pk + base);
      const float4* V4 = (const float4*)(pv + base);
      const float4* qs4 = (const float4*)qs;
      int t0 = c * 64;
#pragma unroll
      for (int i = 0; i < 4; i++) {
        int key = grp + i * 16;
        int tt = t0 + key;
        float4 k4;
        if (tt == S_PAST) {
          k4 = ((const float4*)(qkv + EMB + h * 64))[sub];
          ((float4*)(opk + base))[(size_t)tt * 16 + sub] = k4;
        } else {
          k4 = K4[(size_t)tt * 16 + sub];
        }
        float4 q4 = qs4[sub];
        float p = q4.x * k4.x + q4.y * k4.y + q4.z * k4.z + q4.w * k4.w;
        p += __shfl_xor(p, 1); p += __shfl_xor(p, 2);
        p += __shfl_xor(p, 4); p += __shfl_xor(p, 8);
        if (sub == 0) sc[key] = p * 0.125f + (1.f - mask[tt]) * (-1e9f);
      }
      __syncthreads();
      if (wid == 0) {
        float a = sc[lane];
        float m = a;
#pragma unroll
        for (int o = 32; o > 0; o >>= 1) m = fmaxf(m, __shfl_down(m, o));
        m = __shfl(m, 0);
        float ea = expf(a - m);
        sc[lane] = ea;
        float s = ea;
#pragma unroll
        for (int o = 32; o > 0; o >>= 1) s += __shfl_down(s, o);
        if (lane == 0) { part[(h * 16 + c) * 68] = m; part[(h * 16 + c) * 68 + 1] = s; }
      }
      __syncthreads();
      float4 acc = {0.f, 0.f, 0.f, 0.f};
#pragma unroll
      for (int i = 0; i < 4; i++) {
        int key = grp + i * 16;
        int tt = t0 + key;
        float4 v4;
        if (tt == S_PAST) {
          v4 = ((const float4*)(qkv + 2 * EMB + h * 64))[sub];
          ((float4*)(opv + base))[(size_t)tt * 16 + sub] = v4;
        } else {
          v4 = V4[(size_t)tt * 16 + sub];
        }
        float w = sc[key];
        acc.x += w * v4.x; acc.y += w * v4.y; acc.z += w * v4.z; acc.w += w * v4.w;
      }
      acc.x += __shfl_xor(acc.x, 16); acc.y += __shfl_xor(acc.y, 16);
      acc.z += __shfl_xor(acc.z, 16); acc.w += __shfl_xor(acc.w, 16);
      acc.x += __shfl_xor(acc.x, 32); acc.y += __shfl_xor(acc.y, 32);
      acc.z += __shfl_xor(acc.z, 32); acc.w += __shfl_xor(acc.w, 32);
      if (lane < 16) redo[wid * 16 + lane] = acc;
      __syncthreads();
      if (tid < 16) {
        float4 a0 = redo[tid], a1 = redo[16 + tid], a2 = redo[32 + tid], a3 = redo[48 + tid];
        float4 r;
        r.x = a0.x + a1.x + a2.x + a3.x;
        r.y = a0.y + a1.y + a2.y + a3.y;
        r.z = a0.z + a1.z + a2.z + a3.z;
        r.w = a0.w + a1.w + a2.w + a3.w;
        ((float4*)(part + (h * 16 + c) * 68 + 4))[tid] = r;
      }
      __syncthreads();
    } else {
      int k = t - 192;   // 0..11: seed fc bias for this layer's S4
      wfc[k * 256 + tid] = fc_b[l * E4 + k * 256 + tid];
    }
  }
}

__device__ void stage_proj(int bi, const float* part, const float* W, const float* pb,
                           const float* attn_b, float* hout, float* qkv, int l, float* sm) {
  const int NT = (l < NL - 1) ? 153 : 144;
  int tid = threadIdx.x;
  for (int t = bi; t < NT; t += NCOMP) {
    if (t < 144) {
      int h = t / 12, rem = t % 12;
      int esub = rem / 3, jt = rem % 3;
      float* xs = sm + 1024;
      float4* red4 = (float4*)sm;
      if (tid < 16) {
        float M = -1e30f;
#pragma unroll
        for (int cc = 0; cc < 16; cc++) M = fmaxf(M, part[(h * 16 + cc) * 68]);
        float T = 0.f, o = 0.f;
        int d = esub * 16 + tid;
#pragma unroll
        for (int cc = 0; cc < 16; cc++) {
          float w = expf(part[(h * 16 + cc) * 68] - M);
          T += part[(h * 16 + cc) * 68 + 1] * w;
          o += part[(h * 16 + cc) * 68 + 4 + d] * w;
        }
        xs[tid] = o / T;
      }
      __syncthreads();
      const int n4 = EMB >> 2;
      int r0 = h * 64 + esub * 16, c0 = jt * 256;
      const float4* W4 = (const float4*)(W + (size_t)l * EMB * EMB) + (size_t)r0 * n4 + (c0 >> 2);
      const float* bias = (h == 0 && esub == 0) ? (pb + l * EMB + c0) : nullptr;
      gemv_rows(16, xs, W4, n4, hout + c0, red4, bias);
    } else {
      int k = t - 144;   // 0..8: seed next layer's qkv bias
      qkv[k * 256 + tid] = attn_b[(l + 1) * E3 + k * 256 + tid];
    }
  }
}

__device__ void stage_mlp(int bi, const float* fcv, const float* W, const float* mb,
                          float* hout, int l, float* sm) {
  const int NT = 384;
  int tid = threadIdx.x;
  for (int t = bi; t < NT; t += NCOMP) {
    int jt = t % 3, et = t / 3;
    int r0 = et * 24, c0 = jt * 256;
    float* xs = sm + 1024;
    float4* red4 = (float4*)sm;
    if (tid < 24) {
      float x = fcv[r0 + tid];
      xs[tid] = 0.5f * x * (1.f + tanhf(0.7978845608028654f * (x + 0.044715f * x * x * x)));
    }
    __syncthreads();
    const int n4 = EMB >> 2;
    const float4* W4 = (const float4*)(W + (size_t)l * E4 * EMB) + (size_t)r0 * n4 + (c0 >> 2);
    const float* bias = (et == 0) ? (mb + l * EMB + c0) : nullptr;
    gemv_rows(24, xs, W4, n4, hout + c0, red4, bias);
  }
}

__device__ void stage_logits(int bi, const float* h, const float* g, const float* b,
                             const float* wte, float* out, float* sm) {
  float* xs = sm;
  volatile float* ra = sm + 1088; volatile float* rb = sm + 1092;
  float mean, rstd;
  ln_stats(h, ra, rb, mean, rstd);
  int tid = threadIdx.x;
  for (int e = tid; e < EMB; e += 256) xs[e] = (h[e] - mean) * rstd * g[e] + b[e];
  __syncthreads();
  const float4* xs4 = (const float4*)xs;
  int lane = tid & 63, wid = tid >> 6;
  for (int t = bi; t < 12565; t += NCOMP) {
    int v = t * 4 + wid;
    if (v < NV) {
      const float4* row = (const float4*)(wte + (size_t)v * EMB);
      float acc = 0.f;
#pragma unroll
      for (int i = 0; i < 3; i++) {
        float4 a = row[lane + 64 * i], x = xs4[lane + 64 * i];
        acc += a.x * x.x + a.y * x.y + a.z * x.z + a.w * x.w;
      }
#pragma unroll
      for (int o = 32; o > 0; o >>= 1) acc += __shfl_down(acc, o);
      if (lane == 0) out[v] = acc;
    }
  }
}

// background copy: 128 blocks stream past_key/past_value -> out (skip slot S_PAST)
__device__ void do_copy(int cb, const float* pk, const float* pv, float* opk, float* opv) {
  const size_t n4 = (size_t)NL * NH * MAXS * HD / 4;
  for (size_t i = (size_t)cb * 256 + threadIdx.x; i < 2 * n4; i += (size_t)NCOPY * 256) {
    size_t j = (i < n4) ? i : i - n4;
    int tt = (int)((j >> 4) & (MAXS - 1));
    if (tt != S_PAST) {
      if (i < n4) ((float4*)opk)[j] = ((const float4*)pk)[j];
      else        ((float4*)opv)[j] = ((const float4*)pv)[j];
    }
  }
}

__global__ __launch_bounds__(256, 2) void gpt2_mega(
    const int* ids, const float* pk, const float* pv, const float* mask,
    const float* wte, const float* wpe,
    const float* ln1_g, const float* ln1_b, const float* attn_w, const float* attn_b,
    const float* proj_w, const float* proj_b, const float* ln2_g, const float* ln2_b,
    const float* fc_w, const float* fc_b, const float* mlp_w, const float* mlp_b,
    const float* lnf_g, const float* lnf_b,
    float* out_logits, float* opk, float* opv, float* ws) {
  int bi = blockIdx.x;
  if (bi >= NCOMP) { do_copy(bi - NCOMP, pk, pv, opk, opv); return; }

  __shared__ float sm[1104];
  uint32* cnt = (uint32*)(ws + WS_SYNC);
  float* wh = ws + WS_H;
  float* wqkv = ws + WS_QKV;
  float* wfc = ws + WS_FC;
  float* wpart = ws + WS_PART;

  int st = 0;
  stage_embed(bi, ids, wte, wpe, attn_b, wh, wqkv);
  gbar(cnt, st++);
  for (int l = 0; l < NL; l++) {
    stage_ln_gemv(bi, wh, ln1_g, ln1_b, attn_w, wqkv, E3, l, 9, sm);
    gbar(cnt, st++);
    stage_attn(bi, wqkv, pk, pv, mask, fc_b, opk, opv, wpart, wfc, l, sm);
    gbar(cnt, st++);
    stage_proj(bi, wpart, proj_w, proj_b, attn_b, wh, wqkv, l, sm);
    gbar(cnt, st++);
    stage_ln_gemv(bi, wh, ln2_g, ln2_b, fc_w, wfc, E4, l, 12, sm);
    gbar(cnt, st++);
    stage_mlp(bi, wfc, mlp_w, mlp_b, wh, l, sm);
    gbar(cnt, st++);
  }
  stage_logits(bi, wh, lnf_g, lnf_b, wte, out_logits, sm);
}

extern "C" void kernel_launch(void* const* d_in, const int* in_sizes, int n_in,
                              void* d_out, int out_size, void* d_ws, size_t ws_size,
                              hipStream_t stream) {
  const int* input_ids = (const int*)d_in[0];
  const float* past_key = (const float*)d_in[1];
  const float* past_value = (const float*)d_in[2];
  const float* mask = (const float*)d_in[4];
  const float* wte = (const float*)d_in[5];
  const float* wpe = (const float*)d_in[6];
  const float* ln1_g = (const float*)d_in[7];
  const float* ln1_b = (const float*)d_in[8];
  const float* attn_w = (const float*)d_in[9];
  const float* attn_b = (const float*)d_in[10];
  const float* proj_w = (const float*)d_in[11];
  const float* proj_b = (const float*)d_in[12];
  const float* ln2_g = (const float*)d_in[13];
  const float* ln2_b = (const float*)d_in[14];
  const float* fc_w = (const float*)d_in[15];
  const float* fc_b = (const float*)d_in[16];
  const float* mlp_w = (const float*)d_in[17];
  const float* mlp_b = (const float*)d_in[18];
  const float* lnf_g = (const float*)d_in[19];
  const float* lnf_b = (const float*)d_in[20];

  float* out = (float*)d_out;
  float* out_logits = out;
  float* out_pk = out + NV;
  float* out_pv = out_pk + (size_t)NL * NH * MAXS * HD;

  // zero the barrier counters (must happen every call; graph-captured as memset node)
  hipMemsetAsync(d_ws, 0, 128 * sizeof(uint32), stream);

  gpt2_mega<<<NBLK, 256, 0, stream>>>(
      input_ids, past_key, past_value, mask, wte, wpe,
      ln1_g, ln1_b, attn_w, attn_b, proj_w, proj_b, ln2_g, ln2_b,
      fc_w, fc_b, mlp_w, mlp_b, lnf_g, lnf_b,
      out_logits, out_pk, out_pv, (float*)d_ws);
}

// Round 4
// 444.639 us; speedup vs baseline: 11.4957x; 11.4957x over previous
//
#include <hip/hip_runtime.h>
#include <math.h>

#define EMB 768
#define NH 12
#define HD 64
#define NL 12
#define NV 50257
#define MAXS 1024
#define S_PAST 1023
#define E3 2304
#define E4 3072

// workspace float offsets
#define WS_H    0
#define WS_QKV  768
#define WS_FC   3072
#define WS_PART 6144   // 96 entries * 68 floats

__device__ __forceinline__ void blockReduce2(float& a, float& b, volatile float* ra, volatile float* rb) {
  int lane = threadIdx.x & 63, wid = threadIdx.x >> 6;
#pragma unroll
  for (int o = 32; o > 0; o >>= 1) { a += __shfl_down(a, o); b += __shfl_down(b, o); }
  if (lane == 0) { ra[wid] = a; rb[wid] = b; }
  __syncthreads();
  if (threadIdx.x == 0) {
    ra[0] = ra[0] + ra[1] + ra[2] + ra[3];
    rb[0] = rb[0] + rb[1] + rb[2] + rb[3];
  }
  __syncthreads();
  a = ra[0]; b = rb[0];
}

// h = wte[id] + wpe[S]; seed qkv with attn_b[layer 0]
__global__ void embed_kernel(const int* __restrict__ ids, const float* __restrict__ wte,
                             const float* __restrict__ wpe, const float* __restrict__ attn_b,
                             float* __restrict__ hvec, float* __restrict__ qkv) {
  int idx = blockIdx.x * 256 + threadIdx.x;
  if (idx < E3) qkv[idx] = attn_b[idx];
  if (idx < EMB) {
    int id = ids[0];
    hvec[idx] = wte[(size_t)id * EMB + idx] + wpe[(size_t)S_PAST * EMB + idx];
  }
}

// out[j] += sum_e LN(h)[e] * W[l][e][j]; 64 rows x 256 cols per block.
// Two-phase: 16 float4 loads into registers, then FMA (keeps ~16KB/wave in flight).
__global__ void ln_gemv4(const float* __restrict__ hvec, const float* __restrict__ g,
                         const float* __restrict__ bb, const float* __restrict__ W,
                         float* __restrict__ out, int N, int l) {
  __shared__ float lh[EMB];
  __shared__ float xs[64];
  __shared__ float ra[4], rb[4];
  __shared__ float4 red[4][64];
  int tid = threadIdx.x, lane = tid & 63, wid = tid >> 6;
  float s1 = 0.f, s2 = 0.f;
  for (int e = tid; e < EMB; e += 256) { float v = hvec[e]; lh[e] = v; s1 += v; s2 += v * v; }
  blockReduce2(s1, s2, ra, rb);
  float mean = s1 * (1.f / EMB);
  float var = s2 * (1.f / EMB) - mean * mean;
  float rstd = rsqrtf(var + 1e-5f);
  int e0 = blockIdx.y * 64;
  if (tid < 64) {
    int e = e0 + tid;
    xs[tid] = (lh[e] - mean) * rstd * g[l * EMB + e] + bb[l * EMB + e];
  }
  __syncthreads();
  int j4 = blockIdx.x * 64 + lane;
  int N4 = N >> 2;
  const float4* W4 = (const float4*)(W + (size_t)l * EMB * N) + (size_t)e0 * N4 + j4;
  const float4* p = W4 + (size_t)wid * N4;   // rows wid + 4*i
  float4 w[16];
#pragma unroll
  for (int i = 0; i < 16; i++) w[i] = p[(size_t)(i * 4) * N4];
  float4 acc = {0.f, 0.f, 0.f, 0.f};
#pragma unroll
  for (int i = 0; i < 16; i++) {
    float x = xs[wid + i * 4];
    acc.x += x * w[i].x; acc.y += x * w[i].y; acc.z += x * w[i].z; acc.w += x * w[i].w;
  }
  red[wid][lane] = acc;
  __syncthreads();
  if (wid == 0) {
    float4 a0 = red[0][lane], a1 = red[1][lane], a2 = red[2][lane], a3 = red[3][lane];
    float rx = a0.x + a1.x + a2.x + a3.x;
    float ry = a0.y + a1.y + a2.y + a3.y;
    float rz = a0.z + a1.z + a2.z + a3.z;
    float rw = a0.w + a1.w + a2.w + a3.w;
    float* op = out + (size_t)j4 * 4;
    atomicAdd(op + 0, rx); atomicAdd(op + 1, ry);
    atomicAdd(op + 2, rz); atomicAdd(op + 3, rw);
  }
}

// attention partials for one (head, 128-key chunk); also copies K/V rows to outputs
__global__ void attn_kv(const float* __restrict__ qkv, const float* __restrict__ pk,
                        const float* __restrict__ pv, const float* __restrict__ mask,
                        float* __restrict__ opk, float* __restrict__ opv,
                        float* __restrict__ part, int l) {
  int h = blockIdx.x >> 3, c = blockIdx.x & 7;
  int tid = threadIdx.x, lane = tid & 63, wid = tid >> 6;
  int sub = tid & 15, grp = tid >> 4;
  __shared__ float4 qs4[16];
  __shared__ float sc[128];
  __shared__ float4 redo[4][16];
  if (tid < 16) qs4[tid] = ((const float4*)(qkv + h * 64))[tid];
  __syncthreads();
  size_t base = ((size_t)(l * NH + h) * MAXS) * HD;
  const float4* K4 = (const float4*)(pk + base);
  const float4* V4 = (const float4*)(pv + base);
  float4* oK4 = (float4*)(opk + base);
  float4* oV4 = (float4*)(opv + base);
  int t0 = c * 128;
  float4 kreg[8];
#pragma unroll
  for (int i = 0; i < 8; i++) {
    int t = t0 + grp + i * 16;
    kreg[i] = (t == S_PAST) ? ((const float4*)(qkv + EMB + h * 64))[sub] : K4[(size_t)t * 16 + sub];
  }
#pragma unroll
  for (int i = 0; i < 8; i++) {
    int t = t0 + grp + i * 16;
    oK4[(size_t)t * 16 + sub] = kreg[i];
  }
  float4 q4 = qs4[sub];
#pragma unroll
  for (int i = 0; i < 8; i++) {
    int key = grp + i * 16;
    float p = q4.x * kreg[i].x + q4.y * kreg[i].y + q4.z * kreg[i].z + q4.w * kreg[i].w;
    p += __shfl_xor(p, 1); p += __shfl_xor(p, 2);
    p += __shfl_xor(p, 4); p += __shfl_xor(p, 8);
    if (sub == 0) sc[key] = p * 0.125f + (1.f - mask[t0 + key]) * (-1e9f);
  }
  __syncthreads();
  if (wid == 0) {
    float a = sc[lane], b2 = sc[lane + 64];
    float m = fmaxf(a, b2);
#pragma unroll
    for (int o = 32; o > 0; o >>= 1) m = fmaxf(m, __shfl_down(m, o));
    m = __shfl(m, 0);
    float ea = expf(a - m), eb = expf(b2 - m);
    sc[lane] = ea; sc[lane + 64] = eb;
    float s = ea + eb;
#pragma unroll
    for (int o = 32; o > 0; o >>= 1) s += __shfl_down(s, o);
    if (lane == 0) { part[(h * 8 + c) * 68 + 0] = m; part[(h * 8 + c) * 68 + 1] = s; }
  }
  __syncthreads();
  float4 vreg[8];
#pragma unroll
  for (int i = 0; i < 8; i++) {
    int t = t0 + grp + i * 16;
    vreg[i] = (t == S_PAST) ? ((const float4*)(qkv + 2 * EMB + h * 64))[sub] : V4[(size_t)t * 16 + sub];
  }
#pragma unroll
  for (int i = 0; i < 8; i++) {
    int t = t0 + grp + i * 16;
    oV4[(size_t)t * 16 + sub] = vreg[i];
  }
  float4 acc = {0.f, 0.f, 0.f, 0.f};
#pragma unroll
  for (int i = 0; i < 8; i++) {
    float w = sc[grp + i * 16];
    acc.x += w * vreg[i].x; acc.y += w * vreg[i].y; acc.z += w * vreg[i].z; acc.w += w * vreg[i].w;
  }
  acc.x += __shfl_xor(acc.x, 16); acc.y += __shfl_xor(acc.y, 16);
  acc.z += __shfl_xor(acc.z, 16); acc.w += __shfl_xor(acc.w, 16);
  acc.x += __shfl_xor(acc.x, 32); acc.y += __shfl_xor(acc.y, 32);
  acc.z += __shfl_xor(acc.z, 32); acc.w += __shfl_xor(acc.w, 32);
  if (lane < 16) redo[wid][lane] = acc;
  __syncthreads();
  if (tid < 16) {
    float4 a0 = redo[0][tid], a1 = redo[1][tid], a2 = redo[2][tid], a3 = redo[3][tid];
    float4 r;
    r.x = a0.x + a1.x + a2.x + a3.x;
    r.y = a0.y + a1.y + a2.y + a3.y;
    r.z = a0.z + a1.z + a2.z + a3.z;
    r.w = a0.w + a1.w + a2.w + a3.w;
    ((float4*)(part + (h * 8 + c) * 68 + 4))[tid] = r;
  }
}

// combine 8 chunk-partials for head h, then h += attn_out(head) @ proj_w[rows of head]
__global__ void proj_attn(const float* __restrict__ part, const float* __restrict__ W,
                          const float* __restrict__ bias, const float* __restrict__ fc_b,
                          float* __restrict__ hout, float* __restrict__ wfc, int l) {
  int jb = blockIdx.x;   // 0..2
  int h = blockIdx.y;    // 0..11
  int tid = threadIdx.x, lane = tid & 63, wid = tid >> 6;
  __shared__ float xs[64];
  __shared__ float4 red[4][64];
  if (tid < 64) {
    float M = -1e30f;
    for (int cc = 0; cc < 8; cc++) M = fmaxf(M, part[(h * 8 + cc) * 68]);
    float T = 0.f, o = 0.f;
    for (int cc = 0; cc < 8; cc++) {
      float w = expf(part[(h * 8 + cc) * 68] - M);
      T += part[(h * 8 + cc) * 68 + 1] * w;
      o += part[(h * 8 + cc) * 68 + 4 + tid] * w;
    }
    xs[tid] = o / T;
  }
  int bid = h * 3 + jb;
  if (bid < 12) wfc[bid * 256 + tid] = fc_b[l * E4 + bid * 256 + tid];
  __syncthreads();
  int j4 = jb * 64 + lane;
  const int N4 = EMB >> 2;
  const float4* W4 = (const float4*)(W + (size_t)l * EMB * EMB) + (size_t)(h * 64) * N4 + j4;
  const float4* p = W4 + (size_t)wid * N4;
  float4 w[16];
#pragma unroll
  for (int i = 0; i < 16; i++) w[i] = p[(size_t)(i * 4) * N4];
  float4 acc = {0.f, 0.f, 0.f, 0.f};
#pragma unroll
  for (int i = 0; i < 16; i++) {
    float x = xs[wid + i * 4];
    acc.x += x * w[i].x; acc.y += x * w[i].y; acc.z += x * w[i].z; acc.w += x * w[i].w;
  }
  red[wid][lane] = acc;
  __syncthreads();
  if (wid == 0) {
    float4 a0 = red[0][lane], a1 = red[1][lane], a2 = red[2][lane], a3 = red[3][lane];
    float rx = a0.x + a1.x + a2.x + a3.x;
    float ry = a0.y + a1.y + a2.y + a3.y;
    float rz = a0.z + a1.z + a2.z + a3.z;
    float rw = a0.w + a1.w + a2.w + a3.w;
    if (h == 0) {
      const float* bp = bias + l * EMB + j4 * 4;
      rx += bp[0]; ry += bp[1]; rz += bp[2]; rw += bp[3];
    }
    float* op = hout + (size_t)j4 * 4;
    atomicAdd(op + 0, rx); atomicAdd(op + 1, ry);
    atomicAdd(op + 2, rz); atomicAdd(op + 3, rw);
  }
}

// h[j] += sum_e gelu(fc[e]) * mlp_w[l][e][j]; 128 rows per block (two 16-load batches)
__global__ void mlp_gemv4(const float* __restrict__ fcv, const float* __restrict__ W,
                          const float* __restrict__ bias, const float* __restrict__ attn_b,
                          float* __restrict__ hout, float* __restrict__ qkv, int l) {
  __shared__ float xs[128];
  __shared__ float4 red[4][64];
  int tid = threadIdx.x, lane = tid & 63, wid = tid >> 6;
  int e0 = blockIdx.y * 128;
  if (tid < 128) {
    float x = fcv[e0 + tid];
    xs[tid] = 0.5f * x * (1.f + tanhf(0.7978845608028654f * (x + 0.044715f * x * x * x)));
  }
  int bid = blockIdx.y * 3 + blockIdx.x;
  if (l + 1 < NL && bid < 9) qkv[bid * 256 + tid] = attn_b[(l + 1) * E3 + bid * 256 + tid];
  __syncthreads();
  int j4 = blockIdx.x * 64 + lane;
  const int N4 = EMB >> 2;
  const float4* W4 = (const float4*)(W + (size_t)l * E4 * EMB) + (size_t)e0 * N4 + j4;
  float4 acc = {0.f, 0.f, 0.f, 0.f};
#pragma unroll
  for (int b = 0; b < 2; b++) {
    const float4* p = W4 + (size_t)(b * 64 + wid) * N4;
    float4 w[16];
#pragma unroll
    for (int i = 0; i < 16; i++) w[i] = p[(size_t)(i * 4) * N4];
#pragma unroll
    for (int i = 0; i < 16; i++) {
      float x = xs[b * 64 + wid + i * 4];
      acc.x += x * w[i].x; acc.y += x * w[i].y; acc.z += x * w[i].z; acc.w += x * w[i].w;
    }
  }
  red[wid][lane] = acc;
  __syncthreads();
  if (wid == 0) {
    float4 a0 = red[0][lane], a1 = red[1][lane], a2 = red[2][lane], a3 = red[3][lane];
    float rx = a0.x + a1.x + a2.x + a3.x;
    float ry = a0.y + a1.y + a2.y + a3.y;
    float rz = a0.z + a1.z + a2.z + a3.z;
    float rw = a0.w + a1.w + a2.w + a3.w;
    if (blockIdx.y == 0) {
      const float* bp = bias + l * EMB + j4 * 4;
      rx += bp[0]; ry += bp[1]; rz += bp[2]; rw += bp[3];
    }
    float* op = hout + (size_t)j4 * 4;
    atomicAdd(op + 0, rx); atomicAdd(op + 1, ry);
    atomicAdd(op + 2, rz); atomicAdd(op + 3, rw);
  }
}

// final LN fused into logits: logits[v] = dot(LN(h), wte[v]); one wave per row
__global__ void logits_lnf(const float* __restrict__ hvec, const float* __restrict__ g,
                           const float* __restrict__ b, const float* __restrict__ wte,
                           float* __restrict__ out) {
  __shared__ float4 xs4[192];
  __shared__ float ra[4], rb[4];
  int tid = threadIdx.x, lane = tid & 63, wid = tid >> 6;
  float s1 = 0.f, s2 = 0.f;
  float v0[3];
  int k = 0;
  for (int e = tid; e < EMB; e += 256, k++) { float v = hvec[e]; v0[k] = v; s1 += v; s2 += v * v; }
  blockReduce2(s1, s2, ra, rb);
  float mean = s1 * (1.f / EMB);
  float var = s2 * (1.f / EMB) - mean * mean;
  float rstd = rsqrtf(var + 1e-5f);
  k = 0;
  for (int e = tid; e < EMB; e += 256, k++)
    ((float*)xs4)[e] = (v0[k] - mean) * rstd * g[e] + b[e];
  __syncthreads();
  int v = blockIdx.x * 4 + wid;
  if (v >= NV) return;
  const float4* row = (const float4*)(wte + (size_t)v * EMB);
  float4 a0 = row[lane], a1 = row[lane + 64], a2 = row[lane + 128];
  float4 x0 = xs4[lane], x1 = xs4[lane + 64], x2 = xs4[lane + 128];
  float acc = a0.x * x0.x + a0.y * x0.y + a0.z * x0.z + a0.w * x0.w
            + a1.x * x1.x + a1.y * x1.y + a1.z * x1.z + a1.w * x1.w
            + a2.x * x2.x + a2.y * x2.y + a2.z * x2.z + a2.w * x2.w;
#pragma unroll
  for (int o = 32; o > 0; o >>= 1) acc += __shfl_down(acc, o);
  if (lane == 0) out[v] = acc;
}

extern "C" void kernel_launch(void* const* d_in, const int* in_sizes, int n_in,
                              void* d_out, int out_size, void* d_ws, size_t ws_size,
                              hipStream_t stream) {
  const int* input_ids = (const int*)d_in[0];
  const float* past_key = (const float*)d_in[1];
  const float* past_value = (const float*)d_in[2];
  const float* mask = (const float*)d_in[4];
  const float* wte = (const float*)d_in[5];
  const float* wpe = (const float*)d_in[6];
  const float* ln1_g = (const float*)d_in[7];
  const float* ln1_b = (const float*)d_in[8];
  const float* attn_w = (const float*)d_in[9];
  const float* attn_b = (const float*)d_in[10];
  const float* proj_w = (const float*)d_in[11];
  const float* proj_b = (const float*)d_in[12];
  const float* ln2_g = (const float*)d_in[13];
  const float* ln2_b = (const float*)d_in[14];
  const float* fc_w = (const float*)d_in[15];
  const float* fc_b = (const float*)d_in[16];
  const float* mlp_w = (const float*)d_in[17];
  const float* mlp_b = (const float*)d_in[18];
  const float* lnf_g = (const float*)d_in[19];
  const float* lnf_b = (const float*)d_in[20];

  float* out = (float*)d_out;
  float* out_logits = out;
  float* out_pk = out + NV;
  float* out_pv = out_pk + (size_t)NL * NH * MAXS * HD;

  float* ws = (float*)d_ws;
  float* wh = ws + WS_H;
  float* wqkv = ws + WS_QKV;
  float* wfc = ws + WS_FC;
  float* wpart = ws + WS_PART;

  embed_kernel<<<9, 256, 0, stream>>>(input_ids, wte, wpe, attn_b, wh, wqkv);

  for (int l = 0; l < NL; l++) {
    ln_gemv4<<<dim3(9, 12), 256, 0, stream>>>(wh, ln1_g, ln1_b, attn_w, wqkv, E3, l);
    attn_kv<<<96, 256, 0, stream>>>(wqkv, past_key, past_value, mask, out_pk, out_pv, wpart, l);
    proj_attn<<<dim3(3, 12), 256, 0, stream>>>(wpart, proj_w, proj_b, fc_b, wh, wfc, l);
    ln_gemv4<<<dim3(12, 12), 256, 0, stream>>>(wh, ln2_g, ln2_b, fc_w, wfc, E4, l);
    mlp_gemv4<<<dim3(3, 24), 256, 0, stream>>>(wfc, mlp_w, mlp_b, attn_b, wh, wqkv, l);
  }
  logits_lnf<<<12565, 256, 0, stream>>>(wh, lnf_g, lnf_b, wte, out_logits);
}